// Round 8
// baseline (359.375 us; speedup 1.0000x reference)
//
#include <hip/hip_runtime.h>
#include <hip/hip_bf16.h>
#include <stdint.h>

// Problem: B=2, S=4096, E=512, H=8, D=64.  All fp32 in/out; bf16 MFMA inside.
#define LOG2E 1.4426950408889634f
#define NBLK 512

typedef __bf16 bf16;
typedef __bf16 bf16x8 __attribute__((ext_vector_type(8)));
typedef float  f32x4  __attribute__((ext_vector_type(4)));

__device__ __forceinline__ f32x4 mfma16(bf16x8 a, bf16x8 b, f32x4 c) {
    return __builtin_amdgcn_mfma_f32_16x16x32_bf16(a, b, c, 0, 0, 0);
}

__device__ __forceinline__ void async16(const void* g, void* l) {
    __builtin_amdgcn_global_load_lds(
        (const __attribute__((address_space(1))) void*)g,
        (__attribute__((address_space(3))) void*)l, 16, 0, 0);
}

// Single-use grid barrier (one counter per barrier instance, zeroed host-side
// each call).  Device-scope release fence -> arrive -> spin -> acquire fence.
// Safe iff all NBLK blocks are co-resident: guaranteed by launch_bounds(256,2)
// (VGPR<=256 => 2 blocks/CU) x 256 CUs = 512 = grid, per guide §1.
__device__ __forceinline__ void gbar(unsigned int* bar) {
    __syncthreads();
    if (threadIdx.x == 0) {
        __threadfence();   // release: write back dirty L2 (cross-XCD visibility)
        __hip_atomic_fetch_add(bar, 1u, __ATOMIC_ACQ_REL, __HIP_MEMORY_SCOPE_AGENT);
        while (__hip_atomic_load(bar, __ATOMIC_ACQUIRE, __HIP_MEMORY_SCOPE_AGENT)
               != (unsigned int)NBLK)
            __builtin_amdgcn_s_sleep(4);
        __threadfence();   // acquire: invalidate stale L1/L2 lines
    }
    __syncthreads();
}

// ---------------------------------------------------------------------------
// Fused persistent kernel: 4 phases separated by gbar().
//   phase 0: fp32->bf16 convert of X, W_in, W_out        (grid-stride)
//   phase 1: QKV GEMM  (768 128x128 tiles)               (validated r6 body)
//   phase 2: banded flash attention (1024 tiles)         (validated r6 body)
//   phase 3: out projection (256 tiles)                  (validated r6 body)
// 512 blocks x 256 thr, 2 blocks/CU co-resident (LDS 40KB, VGPR<=256).
// ---------------------------------------------------------------------------
__global__ __launch_bounds__(256, 2) void fused_kernel(
    const float* __restrict__ X,  const float* __restrict__ Wi,
    const float* __restrict__ Bi, const float* __restrict__ Wo,
    const float* __restrict__ Bo, const float* __restrict__ T,
    float* OUT, bf16* WS, unsigned int* BAR)
{
    __shared__ __align__(16) bf16 SMEM[20480];   // 40 KB

    bf16* Qb  = WS;
    bf16* Kb  = Qb + 4194304;
    bf16* Vt  = Kb + 4194304;
    bf16* AO  = Vt + 4194304;
    bf16* Xb  = AO + 4194304;
    bf16* Wib = Xb + 4194304;
    bf16* Wob = Wib + 786432;

    const int tid  = threadIdx.x;
    const int blk  = blockIdx.x;
    const int lane = tid & 63;
    const int wv   = tid >> 6;
    const int quad = lane >> 4;
    const int ln   = lane & 15;
    const int srow = tid >> 3;
    const int scc  = tid & 7;

    // ---------------- phase 0: convert ----------------
    for (size_t c = (size_t)blk * 256 + tid; c < 655360; c += (size_t)NBLK * 256) {
        size_t e = c * 8;
        const float* src; bf16* dst; size_t off;
        if (e < 4194304)      { src = X;  dst = Xb;  off = e; }
        else if (e < 4980736) { src = Wi; dst = Wib; off = e - 4194304; }
        else                  { src = Wo; dst = Wob; off = e - 4980736; }
        float4 f0 = *(const float4*)(src + off);
        float4 f1 = *(const float4*)(src + off + 4);
        bf16x8 v = { (bf16)f0.x,(bf16)f0.y,(bf16)f0.z,(bf16)f0.w,
                     (bf16)f1.x,(bf16)f1.y,(bf16)f1.z,(bf16)f1.w };
        *(bf16x8*)(dst + off) = v;
    }
    gbar(BAR + 0);

    // ---------------- phase 1: QKV GEMM ----------------
    {
        bf16* As = SMEM;
        bf16* Bs = SMEM + 8192;
        const int wm = (wv >> 1) * 64;
        const int wn = (wv & 1) * 64;

        for (int tl = blk; tl < 768; tl += NBLK) {
            const int bm = tl & 63, bn = tl >> 6;
            const bf16* XA = Xb  + (size_t)bm * 128 * 512;
            const bf16* WB = Wib + (size_t)bn * 128 * 512;

            f32x4 acc[4][4] = {};

            for (int kt = 0; kt < 512; kt += 64) {
                #pragma unroll
                for (int i = 0; i < 4; ++i) {
                    int c   = tid + 256 * i;
                    int row = srow + 32 * i;
                    int cg2 = scc ^ (row & 7);
                    async16(XA + (size_t)row * 512 + kt + cg2 * 8, As + c * 8);
                    async16(WB + (size_t)row * 512 + kt + cg2 * 8, Bs + c * 8);
                }
                __syncthreads();

                bf16x8 af[4][2], bfr[4][2];
                #pragma unroll
                for (int i = 0; i < 4; ++i) {
                    #pragma unroll
                    for (int c = 0; c < 2; ++c) {
                        int ra = wm + i * 16 + ln;
                        af[i][c]  = *(const bf16x8*)&As[(ra * 8 + ((c * 4 + quad) ^ (ra & 7))) * 8];
                        int rb = wn + i * 16 + ln;
                        bfr[i][c] = *(const bf16x8*)&Bs[(rb * 8 + ((c * 4 + quad) ^ (rb & 7))) * 8];
                    }
                }
                #pragma unroll
                for (int c = 0; c < 2; ++c)
                    #pragma unroll
                    for (int i = 0; i < 4; ++i)
                        #pragma unroll
                        for (int j = 0; j < 4; ++j)
                            acc[i][j] = mfma16(af[i][c], bfr[j][c], acc[i][j]);
                __syncthreads();
            }

            #pragma unroll
            for (int i = 0; i < 4; ++i) {
                int mbase = bm * 128 + wm + i * 16 + quad * 4;
                #pragma unroll
                for (int j = 0; j < 4; ++j) {
                    int n = bn * 128 + wn + j * 16 + ln;
                    float bv = Bi[n];
                    int sec = n >> 9;
                    int e = n & 511;
                    int hh = e >> 6, dd = e & 63;
                    #pragma unroll
                    for (int r = 0; r < 4; ++r) {
                        int mm = mbase + r;
                        int b = mm >> 12, s = mm & 4095;
                        bf16 v = (bf16)(acc[i][j][r] + bv);
                        size_t bhi = (size_t)(b * 8 + hh);
                        if (sec == 0)      Qb[(bhi * 4096 + s) * 64 + dd] = v;
                        else if (sec == 1) Kb[(bhi * 4096 + s) * 64 + dd] = v;
                        else               Vt[(bhi * 64 + dd) * 4096 + s] = v;
                    }
                }
            }
        }
    }
    gbar(BAR + 1);

    // ---------------- phase 2: banded attention ----------------
    {
        const float c1 = 0.125f * LOG2E;

        for (int tl = blk; tl < 1024; tl += NBLK) {
            const int qt = tl & 63;
            const int bh = tl >> 6;
            const int h  = bh & 7;
            const int b  = bh >> 3;

            const float t  = T[h];
            const float s2 = t * t;
            const float cb = 1.0f / (2.0f * s2 * s2);

            // band: dist^2 * cb >= 32  =>  dist >= 8*t^2
            const int R  = (int)ceilf(s2 * 8.0f) + 1;
            int lo = qt * 64 - R;      if (lo < 0) lo = 0;     lo &= ~63;
            int hi = qt * 64 + 64 + R; if (hi > 4096) hi = 4096; hi = (hi + 63) & ~63;

            const float c2m = -cb * LOG2E;
            const float c3m = -12.0f * LOG2E;

            const int qrow_f = qt * 64 + wv * 16 + ln;
            const bf16* qptr = Qb + ((size_t)bh * 4096 + qrow_f) * 64 + quad * 8;
            bf16x8 qf0 = *(const bf16x8*)qptr;
            bf16x8 qf1 = *(const bf16x8*)(qptr + 32);

            const int qrow_c = qt * 64 + wv * 16 + quad * 4;
            const float fln = (float)ln;

            f32x4 o[4] = {};
            f32x4 lsum = {};
            const bf16 one = (bf16)1.0f;
            const bf16x8 onesv = { one, one, one, one, one, one, one, one };

            for (int ct = lo; ct < hi; ct += 128) {
                const int ntiles = ((hi - ct) >= 128) ? 2 : 1;
                __syncthreads();   // previous chunk / tile consumed
                #pragma unroll
                for (int tt = 0; tt < 2; ++tt) {
                    if (tt < ntiles) {
                        const bf16* Kg = Kb + ((size_t)bh * 4096 + ct + tt * 64) * 64;
                        const bf16* Vg = Vt + (size_t)bh * 64 * 4096 + ct + tt * 64;
                        bf16* Ksl = SMEM + (tt * 2 + 0) * 4096;
                        bf16* Vsl = SMEM + (tt * 2 + 1) * 4096;
                        #pragma unroll
                        for (int i = 0; i < 2; ++i) {
                            int c = tid + 256 * i;
                            int row = srow + 32 * i;
                            int cg2 = scc ^ (row & 7);
                            async16(Kg + row * 64 + cg2 * 8, Ksl + c * 8);
                            async16(Vg + (size_t)row * 4096 + cg2 * 8, Vsl + c * 8);
                        }
                    }
                }
                __syncthreads();   // staging complete

                for (int tt = 0; tt < ntiles; ++tt) {
                    const int kt = ct + tt * 64;
                    const bf16* Ks = SMEM + tt * 8192;
                    const bf16* Vs = Ks + 4096;
                    bf16* Pw = SMEM + 16384 + wv * 1024;

                    f32x4 sc[4] = {};
                    #pragma unroll
                    for (int tI = 0; tI < 4; ++tI) {
                        int row = tI * 16 + ln;
                        bf16x8 kf0 = *(const bf16x8*)&Ks[(row * 8 + ((quad    ) ^ (row & 7))) * 8];
                        bf16x8 kf1 = *(const bf16x8*)&Ks[(row * 8 + ((4 + quad) ^ (row & 7))) * 8];
                        sc[tI] = mfma16(qf0, kf0, sc[tI]);
                        sc[tI] = mfma16(qf1, kf1, sc[tI]);
                    }

                    float p[4][4];
                    #pragma unroll
                    for (int r = 0; r < 4; ++r) {
                        float Ar = (float)(qrow_c + r - kt) - fln;
                        #pragma unroll
                        for (int tI = 0; tI < 4; ++tI) {
                            float df = Ar - (float)(tI * 16);
                            float lg = fmaf(sc[tI][r], c1, fmaf(df, df * c2m, c3m));
                            p[tI][r] = __builtin_amdgcn_exp2f(lg);
                        }
                    }

                    #pragma unroll
                    for (int tI = 0; tI < 4; ++tI)
                        #pragma unroll
                        for (int r = 0; r < 4; ++r) {
                            int row = quad * 4 + r;
                            int cc  = tI * 2 + (ln >> 3);
                            int idx = row * 64 + ((cc ^ (row & 7)) * 8) + (ln & 7);
                            Pw[idx] = (bf16)p[tI][r];
                        }

                    bf16x8 pf[2];
                    #pragma unroll
                    for (int c = 0; c < 2; ++c)
                        pf[c] = *(const bf16x8*)&Pw[(ln * 8 + ((c * 4 + quad) ^ (ln & 7))) * 8];

                    #pragma unroll
                    for (int c = 0; c < 2; ++c)
                        lsum = mfma16(pf[c], onesv, lsum);
                    #pragma unroll
                    for (int t2 = 0; t2 < 4; ++t2) {
                        int vrow = t2 * 16 + ln;
                        #pragma unroll
                        for (int c = 0; c < 2; ++c) {
                            bf16x8 vf = *(const bf16x8*)&Vs[(vrow * 8 + ((c * 4 + quad) ^ (vrow & 7))) * 8];
                            o[t2] = mfma16(pf[c], vf, o[t2]);
                        }
                    }
                }
            }

            float il[4];
            #pragma unroll
            for (int r = 0; r < 4; ++r) il[r] = __builtin_amdgcn_rcpf(lsum[r]);
            #pragma unroll
            for (int t2 = 0; t2 < 4; ++t2) {
                int dd = t2 * 16 + ln;
                #pragma unroll
                for (int r = 0; r < 4; ++r) {
                    int s = qt * 64 + wv * 16 + quad * 4 + r;
                    AO[((size_t)(b * 4096 + s)) * 512 + h * 64 + dd] = (bf16)(o[t2][r] * il[r]);
                }
            }
        }
    }
    gbar(BAR + 2);

    // ---------------- phase 3: out projection ----------------
    {
        bf16* As = SMEM;
        bf16* Bs = SMEM + 8192;
        const int wm = (wv >> 1) * 64;
        const int wn = (wv & 1) * 64;

        for (int tl = blk; tl < 256; tl += NBLK) {
            const int bm = tl & 63, bn = tl >> 6;
            const bf16* AA = AO  + (size_t)bm * 128 * 512;
            const bf16* WB = Wob + (size_t)bn * 128 * 512;

            f32x4 acc[4][4] = {};

            for (int kt = 0; kt < 512; kt += 64) {
                #pragma unroll
                for (int i = 0; i < 4; ++i) {
                    int c   = tid + 256 * i;
                    int row = srow + 32 * i;
                    int cg2 = scc ^ (row & 7);
                    async16(AA + (size_t)row * 512 + kt + cg2 * 8, As + c * 8);
                    async16(WB + (size_t)row * 512 + kt + cg2 * 8, Bs + c * 8);
                }
                __syncthreads();

                bf16x8 af[4][2], bfr[4][2];
                #pragma unroll
                for (int i = 0; i < 4; ++i) {
                    #pragma unroll
                    for (int c = 0; c < 2; ++c) {
                        int ra = wm + i * 16 + ln;
                        af[i][c]  = *(const bf16x8*)&As[(ra * 8 + ((c * 4 + quad) ^ (ra & 7))) * 8];
                        int rb = wn + i * 16 + ln;
                        bfr[i][c] = *(const bf16x8*)&Bs[(rb * 8 + ((c * 4 + quad) ^ (rb & 7))) * 8];
                    }
                }
                #pragma unroll
                for (int c = 0; c < 2; ++c)
                    #pragma unroll
                    for (int i = 0; i < 4; ++i)
                        #pragma unroll
                        for (int j = 0; j < 4; ++j)
                            acc[i][j] = mfma16(af[i][c], bfr[j][c], acc[i][j]);
                __syncthreads();
            }

            #pragma unroll
            for (int i = 0; i < 4; ++i) {
                int mbase = bm * 128 + wm + i * 16 + quad * 4;
                #pragma unroll
                for (int j = 0; j < 4; ++j) {
                    int n = bn * 128 + wn + j * 16 + ln;
                    float bv = Bo[n];
                    #pragma unroll
                    for (int r = 0; r < 4; ++r)
                        OUT[(size_t)(mbase + r) * 512 + n] = acc[i][j][r] + bv;
                }
            }
        }
    }
}

extern "C" void kernel_launch(void* const* d_in, const int* in_sizes, int n_in,
                              void* d_out, int out_size, void* d_ws, size_t ws_size,
                              hipStream_t stream)
{
    const float* x  = (const float*)d_in[0];
    const float* wi = (const float*)d_in[1];
    const float* bi = (const float*)d_in[2];
    const float* wo = (const float*)d_in[3];
    const float* bo = (const float*)d_in[4];
    const float* t  = (const float*)d_in[5];
    float* out = (float*)d_out;
    bf16* ws   = (bf16*)d_ws;

    // Barrier counters live far past the 36.2 MB of used workspace
    // (ws_size = 256 MiB per the harness's 262144-KB poison fill).
    unsigned int* bar = (unsigned int*)((char*)d_ws + (size_t)192 * 1024 * 1024);
    hipMemsetAsync(bar, 0, 16, stream);

    fused_kernel<<<dim3(NBLK), dim3(256), 0, stream>>>(
        x, wi, bi, wo, bo, t, out, ws, bar);
}

// Round 9
// 124.854 us; speedup vs baseline: 2.8784x; 2.8784x over previous
//
#include <hip/hip_runtime.h>
#include <hip/hip_bf16.h>
#include <stdint.h>

// Problem: B=2, S=4096, E=512, H=8, D=64.  All fp32 in/out; bf16 MFMA inside.
#define LOG2E 1.4426950408889634f

typedef __bf16 bf16;
typedef __bf16 bf16x8 __attribute__((ext_vector_type(8)));
typedef float  f32x4  __attribute__((ext_vector_type(4)));

__device__ __forceinline__ f32x4 mfma16(bf16x8 a, bf16x8 b, f32x4 c) {
    return __builtin_amdgcn_mfma_f32_16x16x32_bf16(a, b, c, 0, 0, 0);
}

__device__ __forceinline__ void async16(const void* g, void* l) {
    __builtin_amdgcn_global_load_lds(
        (const __attribute__((address_space(1))) void*)g,
        (__attribute__((address_space(3))) void*)l, 16, 0, 0);
}

// ---------------------------------------------------------------------------
// Elementwise fp32 -> bf16 convert for X, W_in, W_out (one pass, vectorized).
// ---------------------------------------------------------------------------
__global__ __launch_bounds__(256) void cvt_kernel(
    const float* __restrict__ X, const float* __restrict__ Wi,
    const float* __restrict__ Wo,
    bf16* __restrict__ Xb, bf16* __restrict__ Wib, bf16* __restrict__ Wob)
{
    size_t e = ((size_t)blockIdx.x * 256 + threadIdx.x) * 8;
    const float* src; bf16* dst; size_t off;
    if (e < 4194304)      { src = X;  dst = Xb;  off = e; }
    else if (e < 4980736) { src = Wi; dst = Wib; off = e - 4194304; }
    else                  { src = Wo; dst = Wob; off = e - 4980736; }
    float4 f0 = *(const float4*)(src + off);
    float4 f1 = *(const float4*)(src + off + 4);
    bf16x8 v = { (bf16)f0.x,(bf16)f0.y,(bf16)f0.z,(bf16)f0.w,
                 (bf16)f1.x,(bf16)f1.y,(bf16)f1.z,(bf16)f1.w };
    *(bf16x8*)(dst + off) = v;
}

// ---------------------------------------------------------------------------
// QKV GEMM (bf16): C[8192][1536] = Xb @ Wib^T + bias   (validated r6 body)
// ---------------------------------------------------------------------------
__global__ __launch_bounds__(256) void qkv_gemm_kernel(
    const bf16* __restrict__ Xb, const bf16* __restrict__ Wb,
    const float* __restrict__ bias,
    bf16* __restrict__ Qb, bf16* __restrict__ Kb, bf16* __restrict__ Vt)
{
    const int tid  = threadIdx.x;
    const int lane = tid & 63;
    const int wv   = tid >> 6;
    const int quad = lane >> 4;
    const int ln   = lane & 15;
    const int bm   = blockIdx.x;   // 64
    const int bn   = blockIdx.y;   // 12

    __shared__ __align__(16) bf16 As[128 * 64];
    __shared__ __align__(16) bf16 Bs[128 * 64];

    const int wm = (wv >> 1) * 64;
    const int wn = (wv & 1) * 64;

    const int srow = tid >> 3;   // 0..31
    const int scc  = tid & 7;

    const bf16* XA = Xb + (size_t)bm * 128 * 512;
    const bf16* WB = Wb + (size_t)bn * 128 * 512;

    f32x4 acc[4][4] = {};

    for (int kt = 0; kt < 512; kt += 64) {
        #pragma unroll
        for (int i = 0; i < 4; ++i) {
            int c   = tid + 256 * i;
            int row = srow + 32 * i;
            int cg  = scc ^ (row & 7);
            async16(XA + (size_t)row * 512 + kt + cg * 8, As + c * 8);
            async16(WB + (size_t)row * 512 + kt + cg * 8, Bs + c * 8);
        }
        __syncthreads();   // drains vmcnt

        bf16x8 af[4][2], bfr[4][2];
        #pragma unroll
        for (int i = 0; i < 4; ++i) {
            #pragma unroll
            for (int c = 0; c < 2; ++c) {
                int ra = wm + i * 16 + ln;
                af[i][c]  = *(const bf16x8*)&As[(ra * 8 + ((c * 4 + quad) ^ (ra & 7))) * 8];
                int rb = wn + i * 16 + ln;
                bfr[i][c] = *(const bf16x8*)&Bs[(rb * 8 + ((c * 4 + quad) ^ (rb & 7))) * 8];
            }
        }
        #pragma unroll
        for (int c = 0; c < 2; ++c)
            #pragma unroll
            for (int i = 0; i < 4; ++i)
                #pragma unroll
                for (int j = 0; j < 4; ++j)
                    acc[i][j] = mfma16(af[i][c], bfr[j][c], acc[i][j]);
        __syncthreads();
    }

    #pragma unroll
    for (int i = 0; i < 4; ++i) {
        int mbase = bm * 128 + wm + i * 16 + quad * 4;
        #pragma unroll
        for (int j = 0; j < 4; ++j) {
            int n = bn * 128 + wn + j * 16 + ln;
            float bv = bias[n];
            int sec = n >> 9;
            int e = n & 511;
            int hh = e >> 6, dd = e & 63;
            #pragma unroll
            for (int r = 0; r < 4; ++r) {
                int mm = mbase + r;
                int b = mm >> 12, s = mm & 4095;
                bf16 v = (bf16)(acc[i][j][r] + bv);
                size_t bhi = (size_t)(b * 8 + hh);
                if (sec == 0)      Qb[(bhi * 4096 + s) * 64 + dd] = v;
                else if (sec == 1) Kb[(bhi * 4096 + s) * 64 + dd] = v;
                else               Vt[(bhi * 64 + dd) * 4096 + s] = v;
            }
        }
    }
}

// ---------------------------------------------------------------------------
// Flash attention, BANDED (R = 8*t^2), fixed-max softmax, l via ones-MFMA.
// r6 per-wave body UNCHANGED; q-tile enlarged 64 -> 128 rows (8 waves,
// 512 threads): halves chunk iterations, barriers, and K/V staging bytes.
// Grid: (S/128, B*H) = (32,16) = 512 blocks; 2 blocks/CU (LDS 48 KB).
// ---------------------------------------------------------------------------
__global__ __launch_bounds__(512) void attn_kernel(
    const bf16* __restrict__ Qb, const bf16* __restrict__ Kb,
    const bf16* __restrict__ Vt, const float* __restrict__ T,
    bf16* __restrict__ AO)
{
    const int tid  = threadIdx.x;
    const int lane = tid & 63;
    const int wv   = tid >> 6;        // 0..7
    const int quad = lane >> 4;
    const int ln   = lane & 15;
    const int qt   = blockIdx.x;      // 32 (128 q-rows each)
    const int bh   = blockIdx.y;      // 16
    const int h    = bh & 7;
    const int b    = bh >> 3;

    // KVs: [tile 0/1][K=0,V=1][64*64] = 32 KB ; Ps: 8 waves x 2 KB = 16 KB
    __shared__ __align__(16) bf16 SMEM[24576];   // 48 KB

    const float t  = T[h];
    const float s2 = t * t;
    const float cb = 1.0f / (2.0f * s2 * s2);    // bias = -dist2 * cb

    // band: dist^2 * cb >= 32  =>  dist >= 8*t^2
    const int R  = (int)ceilf(s2 * 8.0f) + 1;
    int lo = qt * 128 - R;       if (lo < 0) lo = 0;     lo &= ~63;
    int hi = qt * 128 + 128 + R; if (hi > 4096) hi = 4096; hi = (hi + 63) & ~63;

    const float c1  = 0.125f * LOG2E;
    const float c2m = -cb * LOG2E;
    const float c3m = -12.0f * LOG2E;

    // Q A-operand fragments (m = lane&15, k = quad*8+j, two 32-k chunks)
    const int qrow_f = qt * 128 + wv * 16 + ln;
    const bf16* qptr = Qb + ((size_t)bh * 4096 + qrow_f) * 64 + quad * 8;
    bf16x8 qf0 = *(const bf16x8*)qptr;
    bf16x8 qf1 = *(const bf16x8*)(qptr + 32);

    const int qrow_c = qt * 128 + wv * 16 + quad * 4;   // C-layout row base
    const float fln = (float)ln;

    f32x4 o[4] = {};
    f32x4 lsum = {};
    const bf16 one = (bf16)1.0f;
    const bf16x8 onesv = { one, one, one, one, one, one, one, one };

    const int srow = tid >> 3;    // 0..63 — covers a full 64-row tile
    const int scc  = tid & 7;

    for (int ct = lo; ct < hi; ct += 128) {
        const int ntiles = ((hi - ct) >= 128) ? 2 : 1;
        __syncthreads();   // previous chunk fully consumed
        #pragma unroll
        for (int tt = 0; tt < 2; ++tt) {
            if (tt < ntiles) {
                const bf16* Kg = Kb + ((size_t)bh * 4096 + ct + tt * 64) * 64;
                const bf16* Vg = Vt + (size_t)bh * 64 * 4096 + ct + tt * 64;
                bf16* Ksl = SMEM + (tt * 2 + 0) * 4096;
                bf16* Vsl = SMEM + (tt * 2 + 1) * 4096;
                int cg = scc ^ (srow & 7);
                async16(Kg + srow * 64 + cg * 8, Ksl + tid * 8);
                async16(Vg + (size_t)srow * 4096 + cg * 8, Vsl + tid * 8);
            }
        }
        __syncthreads();   // staging complete (vmcnt drained at barrier)

        for (int tt = 0; tt < ntiles; ++tt) {
            const int kt = ct + tt * 64;
            const bf16* Ks = SMEM + tt * 8192;
            const bf16* Vs = Ks + 4096;
            bf16* Pw = SMEM + 16384 + wv * 1024;

            // S = Q K^T  (16 q-rows x 64 k-cols)
            f32x4 sc[4] = {};
            #pragma unroll
            for (int tI = 0; tI < 4; ++tI) {
                int row = tI * 16 + ln;
                bf16x8 kf0 = *(const bf16x8*)&Ks[(row * 8 + ((quad    ) ^ (row & 7))) * 8];
                bf16x8 kf1 = *(const bf16x8*)&Ks[(row * 8 + ((4 + quad) ^ (row & 7))) * 8];
                sc[tI] = mfma16(qf0, kf0, sc[tI]);
                sc[tI] = mfma16(qf1, kf1, sc[tI]);
            }

            // fixed-max softmax: p = exp2(s*c1 + d2*c2m + c3m); no reductions
            float p[4][4];
            #pragma unroll
            for (int r = 0; r < 4; ++r) {
                float Ar = (float)(qrow_c + r - kt) - fln;
                #pragma unroll
                for (int tI = 0; tI < 4; ++tI) {
                    float df = Ar - (float)(tI * 16);
                    float lg = fmaf(sc[tI][r], c1, fmaf(df, df * c2m, c3m));
                    p[tI][r] = __builtin_amdgcn_exp2f(lg);
                }
            }

            // P (C-layout) -> LDS -> A-operand layout; wave-private
            #pragma unroll
            for (int tI = 0; tI < 4; ++tI)
                #pragma unroll
                for (int r = 0; r < 4; ++r) {
                    int row = quad * 4 + r;
                    int cc  = tI * 2 + (ln >> 3);
                    int idx = row * 64 + ((cc ^ (row & 7)) * 8) + (ln & 7);
                    Pw[idx] = (bf16)p[tI][r];
                }

            bf16x8 pf[2];
            #pragma unroll
            for (int c = 0; c < 2; ++c)
                pf[c] = *(const bf16x8*)&Pw[(ln * 8 + ((c * 4 + quad) ^ (ln & 7))) * 8];

            // O += P V ; l += P 1  (V^T tile: n=d=lane&15 row, k contiguous)
            #pragma unroll
            for (int c = 0; c < 2; ++c)
                lsum = mfma16(pf[c], onesv, lsum);
            #pragma unroll
            for (int t2 = 0; t2 < 4; ++t2) {
                int vrow = t2 * 16 + ln;
                #pragma unroll
                for (int c = 0; c < 2; ++c) {
                    bf16x8 vf = *(const bf16x8*)&Vs[(vrow * 8 + ((c * 4 + quad) ^ (vrow & 7))) * 8];
                    o[t2] = mfma16(pf[c], vf, o[t2]);
                }
            }
        }
    }

    // epilogue: out[s][h*64+d] = O / l
    float il[4];
    #pragma unroll
    for (int r = 0; r < 4; ++r) il[r] = __builtin_amdgcn_rcpf(lsum[r]);
    #pragma unroll
    for (int t2 = 0; t2 < 4; ++t2) {
        int dd = t2 * 16 + ln;
        #pragma unroll
        for (int r = 0; r < 4; ++r) {
            int s = qt * 128 + wv * 16 + quad * 4 + r;
            AO[((size_t)(b * 4096 + s)) * 512 + h * 64 + dd] = (bf16)(o[t2][r] * il[r]);
        }
    }
}

// ---------------------------------------------------------------------------
// Out projection (bf16): OUT[8192][512] = AO @ Wob^T + bias (validated r6)
// ---------------------------------------------------------------------------
__global__ __launch_bounds__(256) void out_gemm_kernel(
    const bf16* __restrict__ A, const bf16* __restrict__ Wb,
    const float* __restrict__ bias, float* __restrict__ OUT)
{
    const int tid  = threadIdx.x;
    const int lane = tid & 63;
    const int wv   = tid >> 6;
    const int quad = lane >> 4;
    const int ln   = lane & 15;
    const int bm   = blockIdx.x;   // 64
    const int bn   = blockIdx.y;   // 4

    __shared__ __align__(16) bf16 As[128 * 64];
    __shared__ __align__(16) bf16 Bs[128 * 64];

    const int wm = (wv >> 1) * 64;
    const int wn = (wv & 1) * 64;

    const int srow = tid >> 3;
    const int scc  = tid & 7;

    const bf16* AA = A  + (size_t)bm * 128 * 512;
    const bf16* WB = Wb + (size_t)bn * 128 * 512;

    f32x4 acc[4][4] = {};

    for (int kt = 0; kt < 512; kt += 64) {
        #pragma unroll
        for (int i = 0; i < 4; ++i) {
            int c   = tid + 256 * i;
            int row = srow + 32 * i;
            int cg  = scc ^ (row & 7);
            async16(AA + (size_t)row * 512 + kt + cg * 8, As + c * 8);
            async16(WB + (size_t)row * 512 + kt + cg * 8, Bs + c * 8);
        }
        __syncthreads();

        bf16x8 af[4][2], bfr[4][2];
        #pragma unroll
        for (int i = 0; i < 4; ++i) {
            #pragma unroll
            for (int c = 0; c < 2; ++c) {
                int ra = wm + i * 16 + ln;
                af[i][c]  = *(const bf16x8*)&As[(ra * 8 + ((c * 4 + quad) ^ (ra & 7))) * 8];
                int rb = wn + i * 16 + ln;
                bfr[i][c] = *(const bf16x8*)&Bs[(rb * 8 + ((c * 4 + quad) ^ (rb & 7))) * 8];
            }
        }
        #pragma unroll
        for (int c = 0; c < 2; ++c)
            #pragma unroll
            for (int i = 0; i < 4; ++i)
                #pragma unroll
                for (int j = 0; j < 4; ++j)
                    acc[i][j] = mfma16(af[i][c], bfr[j][c], acc[i][j]);
        __syncthreads();
    }

    #pragma unroll
    for (int i = 0; i < 4; ++i) {
        int mbase = bm * 128 + wm + i * 16 + quad * 4;
        #pragma unroll
        for (int j = 0; j < 4; ++j) {
            int n = bn * 128 + wn + j * 16 + ln;
            float bv = bias[n];
            #pragma unroll
            for (int r = 0; r < 4; ++r)
                OUT[(size_t)(mbase + r) * 512 + n] = acc[i][j][r] + bv;
        }
    }
}

extern "C" void kernel_launch(void* const* d_in, const int* in_sizes, int n_in,
                              void* d_out, int out_size, void* d_ws, size_t ws_size,
                              hipStream_t stream)
{
    const float* x  = (const float*)d_in[0];
    const float* wi = (const float*)d_in[1];
    const float* bi = (const float*)d_in[2];
    const float* wo = (const float*)d_in[3];
    const float* bo = (const float*)d_in[4];
    const float* t  = (const float*)d_in[5];
    float* out = (float*)d_out;

    // ws layout (bf16 elements):
    bf16* Qb  = (bf16*)d_ws;          // 4194304
    bf16* Kb  = Qb  + 4194304;        // 4194304
    bf16* Vt  = Kb  + 4194304;        // 4194304
    bf16* AO  = Vt  + 4194304;        // 4194304
    bf16* Xb  = AO  + 4194304;        // 4194304
    bf16* Wib = Xb  + 4194304;        // 786432
    bf16* Wob = Wib + 786432;         // 262144

    cvt_kernel     <<<dim3(2560), 256, 0, stream>>>(x, wi, wo, Xb, Wib, Wob);
    qkv_gemm_kernel<<<dim3(64, 12), 256, 0, stream>>>(Xb, Wib, bi, Qb, Kb, Vt);
    attn_kernel    <<<dim3(32, 16), 512, 0, stream>>>(Qb, Kb, Vt, t, AO);
    out_gemm_kernel<<<dim3(64, 4), 256, 0, stream>>>(AO, Wob, bo, out);
}

// Round 10
// 119.230 us; speedup vs baseline: 3.0141x; 1.0472x over previous
//
#include <hip/hip_runtime.h>
#include <hip/hip_bf16.h>
#include <stdint.h>

// Problem: B=2, S=4096, E=512, H=8, D=64.  All fp32 in/out; bf16 MFMA inside.
#define LOG2E 1.4426950408889634f

typedef __bf16 bf16;
typedef __bf16 bf16x8 __attribute__((ext_vector_type(8)));
typedef __bf16 bf16x4 __attribute__((ext_vector_type(4)));
typedef float  f32x4  __attribute__((ext_vector_type(4)));

__device__ __forceinline__ f32x4 mfma16(bf16x8 a, bf16x8 b, f32x4 c) {
    return __builtin_amdgcn_mfma_f32_16x16x32_bf16(a, b, c, 0, 0, 0);
}

__device__ __forceinline__ void async16(const void* g, void* l) {
    __builtin_amdgcn_global_load_lds(
        (const __attribute__((address_space(1))) void*)g,
        (__attribute__((address_space(3))) void*)l, 16, 0, 0);
}

// ---------------------------------------------------------------------------
// Elementwise fp32 -> bf16 convert for X, W_in, W_out (one pass, vectorized).
// ---------------------------------------------------------------------------
__global__ __launch_bounds__(256) void cvt_kernel(
    const float* __restrict__ X, const float* __restrict__ Wi,
    const float* __restrict__ Wo,
    bf16* __restrict__ Xb, bf16* __restrict__ Wib, bf16* __restrict__ Wob)
{
    size_t e = ((size_t)blockIdx.x * 256 + threadIdx.x) * 8;
    const float* src; bf16* dst; size_t off;
    if (e < 4194304)      { src = X;  dst = Xb;  off = e; }
    else if (e < 4980736) { src = Wi; dst = Wib; off = e - 4194304; }
    else                  { src = Wo; dst = Wob; off = e - 4980736; }
    float4 f0 = *(const float4*)(src + off);
    float4 f1 = *(const float4*)(src + off + 4);
    bf16x8 v = { (bf16)f0.x,(bf16)f0.y,(bf16)f0.z,(bf16)f0.w,
                 (bf16)f1.x,(bf16)f1.y,(bf16)f1.z,(bf16)f1.w };
    *(bf16x8*)(dst + off) = v;
}

// ---------------------------------------------------------------------------
// QKV GEMM (bf16): C[8192][1536] = Xb @ Wib^T + bias   (r6 k-loop body)
// Epilogue: section branch hoisted (block-uniform: bn<4 Q, bn<8 K, else V);
// V-section packs the 4 s-contiguous r-values into one 8B store.
// ---------------------------------------------------------------------------
__global__ __launch_bounds__(256) void qkv_gemm_kernel(
    const bf16* __restrict__ Xb, const bf16* __restrict__ Wb,
    const float* __restrict__ bias,
    bf16* __restrict__ Qb, bf16* __restrict__ Kb, bf16* __restrict__ Vt)
{
    const int tid  = threadIdx.x;
    const int lane = tid & 63;
    const int wv   = tid >> 6;
    const int quad = lane >> 4;
    const int ln   = lane & 15;
    const int bm   = blockIdx.x;   // 64
    const int bn   = blockIdx.y;   // 12

    __shared__ __align__(16) bf16 As[128 * 64];
    __shared__ __align__(16) bf16 Bs[128 * 64];

    const int wm = (wv >> 1) * 64;
    const int wn = (wv & 1) * 64;

    const int srow = tid >> 3;   // 0..31
    const int scc  = tid & 7;

    const bf16* XA = Xb + (size_t)bm * 128 * 512;
    const bf16* WB = Wb + (size_t)bn * 128 * 512;

    f32x4 acc[4][4] = {};

    for (int kt = 0; kt < 512; kt += 64) {
        #pragma unroll
        for (int i = 0; i < 4; ++i) {
            int c   = tid + 256 * i;
            int row = srow + 32 * i;
            int cg  = scc ^ (row & 7);
            async16(XA + (size_t)row * 512 + kt + cg * 8, As + c * 8);
            async16(WB + (size_t)row * 512 + kt + cg * 8, Bs + c * 8);
        }
        __syncthreads();   // drains vmcnt

        bf16x8 af[4][2], bfr[4][2];
        #pragma unroll
        for (int i = 0; i < 4; ++i) {
            #pragma unroll
            for (int c = 0; c < 2; ++c) {
                int ra = wm + i * 16 + ln;
                af[i][c]  = *(const bf16x8*)&As[(ra * 8 + ((c * 4 + quad) ^ (ra & 7))) * 8];
                int rb = wn + i * 16 + ln;
                bfr[i][c] = *(const bf16x8*)&Bs[(rb * 8 + ((c * 4 + quad) ^ (rb & 7))) * 8];
            }
        }
        #pragma unroll
        for (int c = 0; c < 2; ++c)
            #pragma unroll
            for (int i = 0; i < 4; ++i)
                #pragma unroll
                for (int j = 0; j < 4; ++j)
                    acc[i][j] = mfma16(af[i][c], bfr[j][c], acc[i][j]);
        __syncthreads();
    }

    if (bn < 8) {
        // Q or K section: [bh][s][d] stores, 32B-coalesced across ln.
        bf16* DST = (bn < 4) ? Qb : Kb;
        const int nsec = (bn & 3) * 128;
        #pragma unroll
        for (int i = 0; i < 4; ++i) {
            int mbase = bm * 128 + wm + i * 16 + quad * 4;
            #pragma unroll
            for (int j = 0; j < 4; ++j) {
                int e  = nsec + wn + j * 16 + ln;
                int hh = e >> 6, dd = e & 63;
                float bv = bias[(bn < 4 ? 0 : 512) + e];
                #pragma unroll
                for (int r = 0; r < 4; ++r) {
                    int mm = mbase + r;
                    int b = mm >> 12, s = mm & 4095;
                    DST[(((size_t)(b * 8 + hh)) * 4096 + s) * 64 + dd] =
                        (bf16)(acc[i][j][r] + bv);
                }
            }
        }
    } else {
        // V section: V^T[bh][d][s] — the 4 r-values are s-contiguous: pack 8B.
        const int nsec = (bn - 8) * 128;
        #pragma unroll
        for (int i = 0; i < 4; ++i) {
            int mbase = bm * 128 + wm + i * 16 + quad * 4;   // mbase%4==0
            int b = mbase >> 12, s = mbase & 4095;
            #pragma unroll
            for (int j = 0; j < 4; ++j) {
                int e  = nsec + wn + j * 16 + ln;
                int hh = e >> 6, dd = e & 63;
                float bv = bias[1024 + e];
                bf16x4 pk = { (bf16)(acc[i][j][0] + bv), (bf16)(acc[i][j][1] + bv),
                              (bf16)(acc[i][j][2] + bv), (bf16)(acc[i][j][3] + bv) };
                *(bf16x4*)&Vt[(((size_t)(b * 8 + hh)) * 64 + dd) * 4096 + s] = pk;
            }
        }
    }
}

// ---------------------------------------------------------------------------
// Flash attention, BANDED (R = 8*t^2), fixed-max softmax, l via ones-MFMA.
// Validated r9 body, unchanged.
// Grid: (S/128, B*H) = (32,16) = 512 blocks; 2 blocks/CU (LDS 48 KB).
// ---------------------------------------------------------------------------
__global__ __launch_bounds__(512) void attn_kernel(
    const bf16* __restrict__ Qb, const bf16* __restrict__ Kb,
    const bf16* __restrict__ Vt, const float* __restrict__ T,
    bf16* __restrict__ AO)
{
    const int tid  = threadIdx.x;
    const int lane = tid & 63;
    const int wv   = tid >> 6;        // 0..7
    const int quad = lane >> 4;
    const int ln   = lane & 15;
    const int qt   = blockIdx.x;      // 32 (128 q-rows each)
    const int bh   = blockIdx.y;      // 16
    const int h    = bh & 7;
    const int b    = bh >> 3;

    __shared__ __align__(16) bf16 SMEM[24576];   // 48 KB

    const float t  = T[h];
    const float s2 = t * t;
    const float cb = 1.0f / (2.0f * s2 * s2);    // bias = -dist2 * cb

    // band: dist^2 * cb >= 32  =>  dist >= 8*t^2
    const int R  = (int)ceilf(s2 * 8.0f) + 1;
    int lo = qt * 128 - R;       if (lo < 0) lo = 0;     lo &= ~63;
    int hi = qt * 128 + 128 + R; if (hi > 4096) hi = 4096; hi = (hi + 63) & ~63;

    const float c1  = 0.125f * LOG2E;
    const float c2m = -cb * LOG2E;
    const float c3m = -12.0f * LOG2E;

    const int qrow_f = qt * 128 + wv * 16 + ln;
    const bf16* qptr = Qb + ((size_t)bh * 4096 + qrow_f) * 64 + quad * 8;
    bf16x8 qf0 = *(const bf16x8*)qptr;
    bf16x8 qf1 = *(const bf16x8*)(qptr + 32);

    const int qrow_c = qt * 128 + wv * 16 + quad * 4;
    const float fln = (float)ln;

    f32x4 o[4] = {};
    f32x4 lsum = {};
    const bf16 one = (bf16)1.0f;
    const bf16x8 onesv = { one, one, one, one, one, one, one, one };

    const int srow = tid >> 3;    // 0..63
    const int scc  = tid & 7;

    for (int ct = lo; ct < hi; ct += 128) {
        const int ntiles = ((hi - ct) >= 128) ? 2 : 1;
        __syncthreads();
        #pragma unroll
        for (int tt = 0; tt < 2; ++tt) {
            if (tt < ntiles) {
                const bf16* Kg = Kb + ((size_t)bh * 4096 + ct + tt * 64) * 64;
                const bf16* Vg = Vt + (size_t)bh * 64 * 4096 + ct + tt * 64;
                bf16* Ksl = SMEM + (tt * 2 + 0) * 4096;
                bf16* Vsl = SMEM + (tt * 2 + 1) * 4096;
                int cg = scc ^ (srow & 7);
                async16(Kg + srow * 64 + cg * 8, Ksl + tid * 8);
                async16(Vg + (size_t)srow * 4096 + cg * 8, Vsl + tid * 8);
            }
        }
        __syncthreads();

        for (int tt = 0; tt < ntiles; ++tt) {
            const int kt = ct + tt * 64;
            const bf16* Ks = SMEM + tt * 8192;
            const bf16* Vs = Ks + 4096;
            bf16* Pw = SMEM + 16384 + wv * 1024;

            f32x4 sc[4] = {};
            #pragma unroll
            for (int tI = 0; tI < 4; ++tI) {
                int row = tI * 16 + ln;
                bf16x8 kf0 = *(const bf16x8*)&Ks[(row * 8 + ((quad    ) ^ (row & 7))) * 8];
                bf16x8 kf1 = *(const bf16x8*)&Ks[(row * 8 + ((4 + quad) ^ (row & 7))) * 8];
                sc[tI] = mfma16(qf0, kf0, sc[tI]);
                sc[tI] = mfma16(qf1, kf1, sc[tI]);
            }

            float p[4][4];
            #pragma unroll
            for (int r = 0; r < 4; ++r) {
                float Ar = (float)(qrow_c + r - kt) - fln;
                #pragma unroll
                for (int tI = 0; tI < 4; ++tI) {
                    float df = Ar - (float)(tI * 16);
                    float lg = fmaf(sc[tI][r], c1, fmaf(df, df * c2m, c3m));
                    p[tI][r] = __builtin_amdgcn_exp2f(lg);
                }
            }

            #pragma unroll
            for (int tI = 0; tI < 4; ++tI)
                #pragma unroll
                for (int r = 0; r < 4; ++r) {
                    int row = quad * 4 + r;
                    int cc  = tI * 2 + (ln >> 3);
                    int idx = row * 64 + ((cc ^ (row & 7)) * 8) + (ln & 7);
                    Pw[idx] = (bf16)p[tI][r];
                }

            bf16x8 pf[2];
            #pragma unroll
            for (int c = 0; c < 2; ++c)
                pf[c] = *(const bf16x8*)&Pw[(ln * 8 + ((c * 4 + quad) ^ (ln & 7))) * 8];

            #pragma unroll
            for (int c = 0; c < 2; ++c)
                lsum = mfma16(pf[c], onesv, lsum);
            #pragma unroll
            for (int t2 = 0; t2 < 4; ++t2) {
                int vrow = t2 * 16 + ln;
                #pragma unroll
                for (int c = 0; c < 2; ++c) {
                    bf16x8 vf = *(const bf16x8*)&Vs[(vrow * 8 + ((c * 4 + quad) ^ (vrow & 7))) * 8];
                    o[t2] = mfma16(pf[c], vf, o[t2]);
                }
            }
        }
    }

    float il[4];
    #pragma unroll
    for (int r = 0; r < 4; ++r) il[r] = __builtin_amdgcn_rcpf(lsum[r]);
    #pragma unroll
    for (int t2 = 0; t2 < 4; ++t2) {
        int dd = t2 * 16 + ln;
        #pragma unroll
        for (int r = 0; r < 4; ++r) {
            int s = qt * 128 + wv * 16 + quad * 4 + r;
            AO[((size_t)(b * 4096 + s)) * 512 + h * 64 + dd] = (bf16)(o[t2][r] * il[r]);
        }
    }
}

// ---------------------------------------------------------------------------
// Out projection (bf16): OUT[8192][512] = AO @ Wob^T + bias (fp32 out)
// Tile 128x64, grid (64,8)=512 blocks -> 2 blocks/CU for barrier overlap.
// Waves 2x2: wm in {0,64}, wn in {0,32}; acc[4][2].
// ---------------------------------------------------------------------------
__global__ __launch_bounds__(256) void out_gemm_kernel(
    const bf16* __restrict__ A, const bf16* __restrict__ Wb,
    const float* __restrict__ bias, float* __restrict__ OUT)
{
    const int tid  = threadIdx.x;
    const int lane = tid & 63;
    const int wv   = tid >> 6;
    const int quad = lane >> 4;
    const int ln   = lane & 15;
    const int bm   = blockIdx.x;   // 64
    const int bn   = blockIdx.y;   // 8

    __shared__ __align__(16) bf16 As[128 * 64];
    __shared__ __align__(16) bf16 Bs[64 * 64];

    const int wm = (wv >> 1) * 64;
    const int wn = (wv & 1) * 32;

    const int srow = tid >> 3;
    const int scc  = tid & 7;

    const bf16* AA = A  + (size_t)bm * 128 * 512;
    const bf16* WB = Wb + (size_t)bn * 64 * 512;

    f32x4 acc[4][2] = {};

    for (int kt = 0; kt < 512; kt += 64) {
        #pragma unroll
        for (int i = 0; i < 4; ++i) {
            int c   = tid + 256 * i;
            int row = srow + 32 * i;
            int cg  = scc ^ (row & 7);
            async16(AA + (size_t)row * 512 + kt + cg * 8, As + c * 8);
        }
        #pragma unroll
        for (int i = 0; i < 2; ++i) {
            int c   = tid + 256 * i;
            int row = srow + 32 * i;
            int cg  = scc ^ (row & 7);
            async16(WB + (size_t)row * 512 + kt + cg * 8, Bs + c * 8);
        }
        __syncthreads();

        bf16x8 af[4][2], bfr[2][2];
        #pragma unroll
        for (int i = 0; i < 4; ++i)
            #pragma unroll
            for (int c = 0; c < 2; ++c) {
                int ra = wm + i * 16 + ln;
                af[i][c] = *(const bf16x8*)&As[(ra * 8 + ((c * 4 + quad) ^ (ra & 7))) * 8];
            }
        #pragma unroll
        for (int j = 0; j < 2; ++j)
            #pragma unroll
            for (int c = 0; c < 2; ++c) {
                int rb = wn + j * 16 + ln;
                bfr[j][c] = *(const bf16x8*)&Bs[(rb * 8 + ((c * 4 + quad) ^ (rb & 7))) * 8];
            }
        #pragma unroll
        for (int c = 0; c < 2; ++c)
            #pragma unroll
            for (int i = 0; i < 4; ++i)
                #pragma unroll
                for (int j = 0; j < 2; ++j)
                    acc[i][j] = mfma16(af[i][c], bfr[j][c], acc[i][j]);
        __syncthreads();
    }

    #pragma unroll
    for (int i = 0; i < 4; ++i) {
        int mbase = bm * 128 + wm + i * 16 + quad * 4;
        #pragma unroll
        for (int j = 0; j < 2; ++j) {
            int n = bn * 64 + wn + j * 16 + ln;
            float bv = bias[n];
            #pragma unroll
            for (int r = 0; r < 4; ++r)
                OUT[(size_t)(mbase + r) * 512 + n] = acc[i][j][r] + bv;
        }
    }
}

extern "C" void kernel_launch(void* const* d_in, const int* in_sizes, int n_in,
                              void* d_out, int out_size, void* d_ws, size_t ws_size,
                              hipStream_t stream)
{
    const float* x  = (const float*)d_in[0];
    const float* wi = (const float*)d_in[1];
    const float* bi = (const float*)d_in[2];
    const float* wo = (const float*)d_in[3];
    const float* bo = (const float*)d_in[4];
    const float* t  = (const float*)d_in[5];
    float* out = (float*)d_out;

    // ws layout (bf16 elements):
    bf16* Qb  = (bf16*)d_ws;          // 4194304
    bf16* Kb  = Qb  + 4194304;        // 4194304
    bf16* Vt  = Kb  + 4194304;        // 4194304
    bf16* AO  = Vt  + 4194304;        // 4194304
    bf16* Xb  = AO  + 4194304;        // 4194304
    bf16* Wib = Xb  + 4194304;        // 786432
    bf16* Wob = Wib + 786432;         // 262144

    cvt_kernel     <<<dim3(2560), 256, 0, stream>>>(x, wi, wo, Xb, Wib, Wob);
    qkv_gemm_kernel<<<dim3(64, 12), 256, 0, stream>>>(Xb, Wib, bi, Qb, Kb, Vt);
    attn_kernel    <<<dim3(32, 16), 512, 0, stream>>>(Qb, Kb, Vt, t, AO);
    out_gemm_kernel<<<dim3(64, 8), 256, 0, stream>>>(AO, Wob, bo, out);
}